// Round 16
// baseline (480.092 us; speedup 1.0000x reference)
//
#include <hip/hip_runtime.h>

typedef unsigned int uint;
typedef unsigned short ushort_t;
typedef __attribute__((ext_vector_type(4))) float f32x4;
typedef __attribute__((ext_vector_type(2))) float f32x2;
typedef __attribute__((ext_vector_type(8))) short bf16x8;

#define N_USERS 100000
#define N_ITEMS 50000
#define N_NODES 150000
#define N_EDGES 1500000
#define BATCH 4096
#define NSWEEP 4
#define SWEEP_ROWS 37500
#define EP_PAD 96
#define NSB 586              // scan blocks over N_NODES
#define NHIST (NSB * 64)     // 37504
#define WSTRIDE 68           // LDS weight stride (uints): 16B-aligned, 2-way banks

__device__ __forceinline__ uint pack_bf16x2(float a, float b) {
    uint ua = __float_as_uint(a);
    uint ub = __float_as_uint(b);
    ua = (ua + 0x7FFFu + ((ua >> 16) & 1u)) >> 16;
    ub = (ub + 0x7FFFu + ((ub >> 16) & 1u)) >> 16;
    return ua | (ub << 16);
}
__device__ __forceinline__ ushort_t cvt_bf16(float a) {
    uint ua = __float_as_uint(a);
    return (ushort_t)((ua + 0x7FFFu + ((ua >> 16) & 1u)) >> 16);
}
__device__ __forceinline__ float bf_lo(uint u) { return __uint_as_float(u << 16); }
__device__ __forceinline__ float bf_hi(uint u) { return __uint_as_float(u & 0xFFFF0000u); }

// fp8 e4m3 pack/unpack (HW cvt, 2 elems per inst)
__device__ __forceinline__ uint pack_fp8x4(float a, float b, float c, float d) {
    uint r = 0;
    r = (uint)__builtin_amdgcn_cvt_pk_fp8_f32(a, b, (int)r, false);
    r = (uint)__builtin_amdgcn_cvt_pk_fp8_f32(c, d, (int)r, true);
    return r;
}
__device__ __forceinline__ void unpack_fp8x4(uint u, float o[4]) {
    f32x2 lo = __builtin_amdgcn_cvt_pk_f32_fp8((int)u, false);
    f32x2 hi = __builtin_amdgcn_cvt_pk_f32_fp8((int)u, true);
    o[0] = lo.x; o[1] = lo.y; o[2] = hi.x; o[3] = hi.y;
}

// ===== fp8 group gather: 8-lane group per row, lane l = uint4 (16 fp8) ======
__device__ __forceinline__ void gather8_fp8(
    const int2* __restrict__ ep, int st, int d,
    const uint4* __restrict__ s4, int l, float acc[16])
{
    int2 e0 = ep[st];
    int2 e1 = ep[st + 1];
    uint4 g0 = {0u, 0u, 0u, 0u};
    if (0 < d) g0 = s4[(size_t)(uint)e0.x * 8 + l];
    for (int j = 0; j < d; j++) {
        int2 e2 = ep[st + j + 2];
        uint4 g1 = {0u, 0u, 0u, 0u};
        if (j + 1 < d) g1 = s4[(size_t)(uint)e1.x * 8 + l];
        float v = __int_as_float(e0.y);
        float f[4];
        unpack_fp8x4(g0.x, f);
#pragma unroll
        for (int k = 0; k < 4; k++) acc[k]      = fmaf(v, f[k], acc[k]);
        unpack_fp8x4(g0.y, f);
#pragma unroll
        for (int k = 0; k < 4; k++) acc[4 + k]  = fmaf(v, f[k], acc[4 + k]);
        unpack_fp8x4(g0.z, f);
#pragma unroll
        for (int k = 0; k < 4; k++) acc[8 + k]  = fmaf(v, f[k], acc[8 + k]);
        unpack_fp8x4(g0.w, f);
#pragma unroll
        for (int k = 0; k < 4; k++) acc[12 + k] = fmaf(v, f[k], acc[12 + k]);
        e0 = e1; e1 = e2; g0 = g1;
    }
}

// ===== bf16 group gather (pass3): 16-lane group, lane l gathers uint4 ======
template<int PU4>
__device__ __forceinline__ void group_gather(
    const int2* __restrict__ ep, int st, int d, int dmax,
    const uint* __restrict__ src, int l,
    float aLo[4], float aHi[4])
{
    const uint4* s4 = (const uint4*)src;
    bool lok = l < PU4;
    int2 e0 = ep[st];
    int2 e1 = ep[st + 1];
    uint4 g0 = {0u, 0u, 0u, 0u};
    if (lok && 0 < d) g0 = s4[(size_t)(uint)e0.x * PU4 + l];
    for (int j = 0; j < dmax; j++) {
        int2 e2 = ep[st + j + 2];
        uint4 g1 = {0u, 0u, 0u, 0u};
        if (lok && j + 1 < d) g1 = s4[(size_t)(uint)e1.x * PU4 + l];
        float v = (j < d) ? __int_as_float(e0.y) : 0.f;
        aLo[0] = fmaf(v, bf_lo(g0.x), aLo[0]); aHi[0] = fmaf(v, bf_hi(g0.x), aHi[0]);
        aLo[1] = fmaf(v, bf_lo(g0.y), aLo[1]); aHi[1] = fmaf(v, bf_hi(g0.y), aHi[1]);
        aLo[2] = fmaf(v, bf_lo(g0.z), aLo[2]); aHi[2] = fmaf(v, bf_hi(g0.z), aHi[2]);
        aLo[3] = fmaf(v, bf_lo(g0.w), aLo[3]); aHi[3] = fmaf(v, bf_hi(g0.w), aHi[3]);
        e0 = e1; e1 = e2; g0 = g1;
    }
}

// Dual-stream 4-deep per-row variant for pass4 (small): P = 40 uints
__device__ __forceinline__ float2 row_gather_accum_mul(
    const int2* __restrict__ ep, int st, int d,
    const uint* __restrict__ sA, const uint* __restrict__ sB, int lane)
{
    constexpr int P = 40;
    float ax = 0.f, ay = 0.f;
    bool lok = lane < P;
    int2 e0 = ep[st],     e1 = ep[st + 1], e2 = ep[st + 2], e3 = ep[st + 3];
    int2 e4 = ep[st + 4], e5 = ep[st + 5];
    uint a0 = (lok && 0 < d) ? sA[(size_t)e0.x * P + lane] : 0u;
    uint c0 = (lok && 0 < d) ? sB[(size_t)e0.x * P + lane] : 0u;
    uint a1 = (lok && 1 < d) ? sA[(size_t)e1.x * P + lane] : 0u;
    uint c1 = (lok && 1 < d) ? sB[(size_t)e1.x * P + lane] : 0u;
    uint a2 = (lok && 2 < d) ? sA[(size_t)e2.x * P + lane] : 0u;
    uint c2 = (lok && 2 < d) ? sB[(size_t)e2.x * P + lane] : 0u;
    uint a3 = (lok && 3 < d) ? sA[(size_t)e3.x * P + lane] : 0u;
    uint c3 = (lok && 3 < d) ? sB[(size_t)e3.x * P + lane] : 0u;
    for (int j = 0; j < d; j += 2) {
        uint nA4 = (lok && j + 4 < d) ? sA[(size_t)e4.x * P + lane] : 0u;
        uint nC4 = (lok && j + 4 < d) ? sB[(size_t)e4.x * P + lane] : 0u;
        uint nA5 = (lok && j + 5 < d) ? sA[(size_t)e5.x * P + lane] : 0u;
        uint nC5 = (lok && j + 5 < d) ? sB[(size_t)e5.x * P + lane] : 0u;
        int2 n6 = ep[st + j + 6];
        int2 n7 = ep[st + j + 7];
        float v0 = __int_as_float(e0.y);
        ax = fmaf(v0, bf_lo(a0) * bf_lo(c0), ax);
        ay = fmaf(v0, bf_hi(a0) * bf_hi(c0), ay);
        if (j + 1 < d) {
            float v1 = __int_as_float(e1.y);
            ax = fmaf(v1, bf_lo(a1) * bf_lo(c1), ax);
            ay = fmaf(v1, bf_hi(a1) * bf_hi(c1), ay);
        }
        e0 = e2; a0 = a2; c0 = c2; e1 = e3; a1 = a3; c1 = c3;
        e2 = e4; a2 = nA4; c2 = nC4; e3 = e5; a3 = nA5; c3 = nC5;
        e4 = n6; e5 = n7;
    }
    return make_float2(ax, ay);
}

// ============ bf16 feature cast: Xb64 (MFMA A-stream, stride 64 uints) ========
__global__ __launch_bounds__(256) void cast_feats(
    const float* __restrict__ uE, const float* __restrict__ iE,
    uint* __restrict__ Xb64)
{
    int g = blockIdx.x * 256 + threadIdx.x;
    if (g >= N_NODES * 64) return;
    int row = g >> 6, c = g & 63;
    uint outv = 0u;
    if (c < 50) {
        int e0 = c * 2;
        float a, b;
        if (row < N_USERS) { a = uE[(size_t)row * 100 + e0]; b = uE[(size_t)row * 100 + e0 + 1]; }
        else { a = iE[(size_t)(row - N_USERS) * 100 + e0]; b = iE[(size_t)(row - N_USERS) * 100 + e0 + 1]; }
        outv = pack_bf16x2(a, b);
    }
    Xb64[g] = outv;
}

// ============ fp8 feature cast: Xf8 = fp8(16*x), stride 32 uints (128 B) ======
__global__ __launch_bounds__(256) void cast_fp8(
    const float* __restrict__ uE, const float* __restrict__ iE,
    uint* __restrict__ Xf8)
{
    int g = blockIdx.x * 256 + threadIdx.x;
    if (g >= N_NODES * 32) return;
    int row = g >> 5, c = g & 31;
    uint outv = 0u;
    int f0 = c * 4;
    if (f0 < 100) {
        const float* src = (row < N_USERS) ? (uE + (size_t)row * 100)
                                           : (iE + (size_t)(row - N_USERS) * 100);
        outv = pack_fp8x4(src[f0] * 16.f, src[f0 + 1] * 16.f,
                          src[f0 + 2] * 16.f, src[f0 + 3] * 16.f);
    }
    Xf8[g] = outv;
}

// ============ weight prep: wT bf16 [80 cols][64 uints=128 k, zero-padded] =====
__global__ __launch_bounds__(256) void prep_weights(
    const float* __restrict__ W, const float* __restrict__ Wi,
    uint* __restrict__ wtW, uint* __restrict__ wtWi)
{
    int t = blockIdx.x * 256 + threadIdx.x;
    if (t >= 2 * 80 * 64) return;
    const float* src = (t < 80 * 64) ? W : Wi;
    uint* dst = (t < 80 * 64) ? wtW : wtWi;
    int i = t % (80 * 64);
    int col = i >> 6, kk = i & 63;
    int k = kk * 2;
    uint v = 0u;
    if (k < 100) v = pack_bf16x2(src[(size_t)k * 80 + col], src[(size_t)(k + 1) * 80 + col]);
    dst[(size_t)col * 64 + kk] = v;
}

// ======================= CSR construction =======================
// Swept histogram: counter window [lo,hi) = 150 KB stays L2-resident ->
// dirty lines coalesce (R15: one-shot hist had 46 MB WRITE for 600 KB data).
__global__ __launch_bounds__(256) void hist_sweep(
    const int* __restrict__ rows, int* __restrict__ deg, int E, int lo, int hi)
{
    int e = blockIdx.x * 256 + threadIdx.x;
    if (e >= E) return;
    int r = rows[e];
    if (r >= lo && r < hi) atomicAdd(&deg[r], 1);
}

__global__ __launch_bounds__(256) void scan_block(
    const int* __restrict__ deg, int* __restrict__ ptr,
    int* __restrict__ bsum, int n)
{
    __shared__ int s[256];
    int t = threadIdx.x;
    int i = blockIdx.x * 256 + t;
    int v = (i < n) ? deg[i] : 0;
    s[t] = v; __syncthreads();
    for (int off = 1; off < 256; off <<= 1) {
        int x = (t >= off) ? s[t - off] : 0;
        __syncthreads();
        s[t] += x;
        __syncthreads();
    }
    if (i < n) ptr[i] = s[t] - v;
    if (t == 255) bsum[blockIdx.x] = s[255];
}

__global__ __launch_bounds__(1024) void scan_tops(int* __restrict__ bsum, int nb)
{
    __shared__ int s[1024];
    int t = threadIdx.x;
    int v = (t < nb) ? bsum[t] : 0;
    s[t] = v; __syncthreads();
    for (int off = 1; off < 1024; off <<= 1) {
        int x = (t >= off) ? s[t - off] : 0;
        __syncthreads();
        s[t] += x;
        __syncthreads();
    }
    if (t < nb) bsum[t] = s[t] - v;
}

__global__ __launch_bounds__(256) void scan_apply(
    int* __restrict__ ptr, const int* __restrict__ bsum,
    int* __restrict__ pos, int n)
{
    int i = blockIdx.x * 256 + threadIdx.x;
    if (i < n) {
        int p = ptr[i] + bsum[i >> 8];
        ptr[i] = p;
        pos[i] = p;
    }
}

// scan finalize (in place) + optional grand total
__global__ __launch_bounds__(256) void scan_apply_tot(
    int* __restrict__ scanT, const int* __restrict__ bsum,
    const int* __restrict__ orig, int* __restrict__ total, int n)
{
    int i = blockIdx.x * 256 + threadIdx.x;
    if (i < n) {
        int p = scanT[i] + bsum[i >> 8];
        scanT[i] = p;
        if (total && i == n - 1) *total = p + orig[i];
    }
}

// Swept scatter: L2-resident ep window per sweep kills HBM write amplification.
__global__ __launch_bounds__(256) void scatter_sweep(
    const int* __restrict__ rows, const int* __restrict__ cols,
    const float* __restrict__ vals, int* __restrict__ pos,
    int2* __restrict__ ep, int E, int lo, int hi)
{
    int e = blockIdx.x * 256 + threadIdx.x;
    if (e >= E) return;
    int r = rows[e];
    if (r < lo || r >= hi) return;
    int p = atomicAdd(&pos[r], 1);
    ep[p] = make_int2(cols[e], __float_as_int(vals[e]));
}

__global__ __launch_bounds__(128) void pad_ep(int2* __restrict__ ep)
{
    int t = threadIdx.x;
    if (t < EP_PAD) ep[N_EDGES + t] = make_int2(0, 0);
}

// ============== selMap + needed-row marking =====================
__global__ __launch_bounds__(256) void build_selmap(
    const int* __restrict__ userIdx, const int* __restrict__ itemIdx,
    int* __restrict__ selMap)
{
    int i = blockIdx.x * 256 + threadIdx.x;
    if (i < BATCH) selMap[userIdx[i]] = i;
    else if (i < 2 * BATCH) selMap[itemIdx[i - BATCH]] = i;
}

__global__ __launch_bounds__(256) void mark_needed(
    const int* __restrict__ userIdx, const int* __restrict__ itemIdx,
    const int* __restrict__ ptr_, const int* __restrict__ deg_,
    const int2* __restrict__ ep, int* __restrict__ flag)
{
    int i = blockIdx.x * 4 + ((int)threadIdx.x >> 6);
    if (i >= 2 * BATCH) return;
    int lane = threadIdx.x & 63;
    int row = (i < BATCH) ? userIdx[i] : itemIdx[i - BATCH];
    if (lane == 0) flag[row] = 1;
    int st = ptr_[row], d = deg_[row];
    for (int j = lane; j < d; j += 64)
        flag[ep[st + j].x] = 1;
}

// ========= degree bucket sort: LDS hist (bin-major) + flat parallel scan ======
__global__ __launch_bounds__(256) void deg_hist_blk(
    const int* __restrict__ deg, const int* __restrict__ flag,
    int* __restrict__ blockHistT, int n)
{
    __shared__ int h[64];
    int t = threadIdx.x;
    if (t < 64) h[t] = 0;
    __syncthreads();
    int i = blockIdx.x * 256 + t;
    if (i < n && (!flag || flag[i])) {
        int b = deg[i]; if (b > 63) b = 63;
        atomicAdd(&h[b], 1);
    }
    __syncthreads();
    if (t < 64) blockHistT[t * NSB + blockIdx.x] = h[t];
}

__global__ __launch_bounds__(256) void deg_scatter_blk(
    const int* __restrict__ deg, const int* __restrict__ flag,
    const int* __restrict__ scanT, int* __restrict__ sorted, int n)
{
    __shared__ int cnt[64];
    __shared__ int base[64];
    int t = threadIdx.x;
    if (t < 64) { cnt[t] = 0; base[t] = scanT[t * NSB + blockIdx.x]; }
    __syncthreads();
    int i = blockIdx.x * 256 + t;
    if (i < n && (!flag || flag[i])) {
        int b = deg[i]; if (b > 63) b = 63;
        int loc = atomicAdd(&cnt[b], 1);
        sorted[base[b] + loc] = i;
    }
}

// =========== SpMM pass1/pass2: 8-lane groups, fp8 sources, deg-sorted =========

// Pass 1: B1b64 = bf16(L@X); INTf8 = fp8(4096*(L@X .* X))
__global__ __launch_bounds__(256) void spmm_pass1(
    const int* __restrict__ sortedAll,
    const int* __restrict__ ptr_, const int* __restrict__ deg_,
    const int2* __restrict__ ep, const uint* __restrict__ Xf8,
    uint* __restrict__ B1b, uint* __restrict__ INTf8, int N)
{
    int wave = (int)threadIdx.x >> 6, lane = (int)threadIdx.x & 63;
    int grp = lane >> 3, l = lane & 7;
    int si = blockIdx.x * 32 + wave * 8 + grp;
    bool valid = si < N;
    int row = valid ? sortedAll[si] : 0;
    int d = valid ? deg_[row] : 0;
    int st = valid ? ptr_[row] : 0;
    float acc[16];
#pragma unroll
    for (int k = 0; k < 16; k++) acc[k] = 0.f;
    gather8_fp8(ep, st, d, (const uint4*)Xf8, l, acc);
    if (!valid) return;

    uint u[8];
#pragma unroll
    for (int k = 0; k < 8; k++)
        u[k] = pack_bf16x2(acc[2 * k] * 0.0625f, acc[2 * k + 1] * 0.0625f);
    uint4* bdst = (uint4*)(B1b + (size_t)row * 64 + l * 8);
    bdst[0] = make_uint4(u[0], u[1], u[2], u[3]);
    bdst[1] = make_uint4(u[4], u[5], u[6], u[7]);

    uint4 xs4 = ((const uint4*)(Xf8 + (size_t)row * 32))[l];
    float xs[16];
    unpack_fp8x4(xs4.x, xs); unpack_fp8x4(xs4.y, xs + 4);
    unpack_fp8x4(xs4.z, xs + 8); unpack_fp8x4(xs4.w, xs + 12);
    float t[16];
#pragma unroll
    for (int k = 0; k < 16; k++) t[k] = 16.f * acc[k] * xs[k];
    uint4 o;
    o.x = pack_fp8x4(t[0], t[1], t[2], t[3]);
    o.y = pack_fp8x4(t[4], t[5], t[6], t[7]);
    o.z = pack_fp8x4(t[8], t[9], t[10], t[11]);
    o.w = pack_fp8x4(t[12], t[13], t[14], t[15]);
    ((uint4*)(INTf8 + (size_t)row * 32))[l] = o;
}

// Pass 2: B2b64 = bf16(L @ INT)  (INTf8 stores 4096*INT -> descale at output)
__global__ __launch_bounds__(256) void spmm_pass2(
    const int* __restrict__ sortedAll,
    const int* __restrict__ ptr_, const int* __restrict__ deg_,
    const int2* __restrict__ ep, const uint* __restrict__ INTf8,
    uint* __restrict__ B2b, int N)
{
    int wave = (int)threadIdx.x >> 6, lane = (int)threadIdx.x & 63;
    int grp = lane >> 3, l = lane & 7;
    int si = blockIdx.x * 32 + wave * 8 + grp;
    bool valid = si < N;
    int row = valid ? sortedAll[si] : 0;
    int d = valid ? deg_[row] : 0;
    int st = valid ? ptr_[row] : 0;
    float acc[16];
#pragma unroll
    for (int k = 0; k < 16; k++) acc[k] = 0.f;
    gather8_fp8(ep, st, d, (const uint4*)INTf8, l, acc);
    if (!valid) return;
    const float DS = 1.f / 4096.f;
    uint u[8];
#pragma unroll
    for (int k = 0; k < 8; k++)
        u[k] = pack_bf16x2(acc[2 * k] * DS, acc[2 * k + 1] * DS);
    uint4* bdst = (uint4*)(B2b + (size_t)row * 64 + l * 8);
    bdst[0] = make_uint4(u[0], u[1], u[2], u[3]);
    bdst[1] = make_uint4(u[4], u[5], u[6], u[7]);
}

// Pass 3: Lx2 = L@F1 over deg-sorted needed list; bf16 Lxb40 + fp32 Lxsel
__global__ __launch_bounds__(256) void spmm_pass3(
    const int* __restrict__ sorted3, const int* __restrict__ cnt3,
    const int* __restrict__ ptr_, const int* __restrict__ deg_,
    const int2* __restrict__ ep, const uint* __restrict__ F1b,
    const int* __restrict__ selMap,
    uint* __restrict__ Lxb, float* __restrict__ Lxsel)
{
    int wave = (int)threadIdx.x >> 6, lane = (int)threadIdx.x & 63;
    int grp = lane >> 4, l = lane & 15;
    int si = blockIdx.x * 16 + wave * 4 + grp;
    int n3 = *cnt3;
    bool valid = si < n3;
    int row = valid ? sorted3[si] : 0;
    int d = valid ? deg_[row] : 0;
    int st = valid ? ptr_[row] : 0;
    int dm = d, t;
    t = __shfl_xor(dm, 16); dm = dm > t ? dm : t;
    t = __shfl_xor(dm, 32); dm = dm > t ? dm : t;
    float aLo[4] = {0.f, 0.f, 0.f, 0.f}, aHi[4] = {0.f, 0.f, 0.f, 0.f};
    group_gather<10>(ep, st, d, dm, F1b, l, aLo, aHi);
    if (!valid || l >= 10) return;
    uint4 o;
    o.x = pack_bf16x2(aLo[0], aHi[0]); o.y = pack_bf16x2(aLo[1], aHi[1]);
    o.z = pack_bf16x2(aLo[2], aHi[2]); o.w = pack_bf16x2(aLo[3], aHi[3]);
    ((uint4*)(Lxb + (size_t)row * 40))[l] = o;
    int sm = selMap[row];
    if (sm >= 0) {
        float4 f0 = make_float4(aLo[0], aHi[0], aLo[1], aHi[1]);
        float4 f1 = make_float4(aLo[2], aHi[2], aLo[3], aHi[3]);
        ((float4*)(Lxsel + (size_t)sm * 80))[2 * l]     = f0;
        ((float4*)(Lxsel + (size_t)sm * 80))[2 * l + 1] = f1;
    }
}

// Pass 4 (selected rows): B2c[i] = sum_e v * (Lx2[c] .* F1[c]), both bf16
__global__ __launch_bounds__(256) void spmm_pass4(
    const int* __restrict__ ptr_, const int* __restrict__ deg_,
    const int2* __restrict__ ep,
    const uint* __restrict__ Lxb, const uint* __restrict__ F1b,
    const int* __restrict__ userIdx, const int* __restrict__ itemIdx,
    float* __restrict__ outC)
{
    int i = blockIdx.x * 4 + ((int)threadIdx.x >> 6);
    if (i >= 2 * BATCH) return;
    int row = (i < BATCH) ? userIdx[i] : itemIdx[i - BATCH];
    int lane = threadIdx.x & 63;
    float2 r = row_gather_accum_mul(ep, ptr_[row], deg_[row], Lxb, F1b, lane);
    if (lane < 40)
        ((float2*)(outC + (size_t)i * 80))[lane] = r;
}

// ------------- Layer-1 fused linear via MFMA, weights in LDS ----------------
__global__ __launch_bounds__(256) void gemm1_mfma(
    const uint* __restrict__ B1b, const uint* __restrict__ Xb,
    const uint* __restrict__ B2b,
    const uint* __restrict__ wtW, const uint* __restrict__ wtWi,
    const float* __restrict__ b, const float* __restrict__ bi,
    const int* __restrict__ selMap,
    ushort_t* __restrict__ F1b, float* __restrict__ F1sel, int N)
{
    __shared__ uint sW[80 * WSTRIDE];
    __shared__ uint sWi[80 * WSTRIDE];
    for (int i = threadIdx.x; i < 80 * 64; i += 256) {
        int col = i >> 6, kk = i & 63;
        sW[col * WSTRIDE + kk]  = wtW[i];
        sWi[col * WSTRIDE + kk] = wtWi[i];
    }
    __syncthreads();

    int wave = (int)threadIdx.x >> 6;
    int lane = (int)threadIdx.x & 63;
    int rowBase = blockIdx.x * 64 + wave * 16;
    int colLocal = lane & 15;
    int q = lane >> 4;
    int arow = rowBase + colLocal;
    bool rowOK = arow < N;

    f32x4 acc[5];
#pragma unroll
    for (int nt = 0; nt < 5; nt++) acc[nt] = (f32x4){0.f, 0.f, 0.f, 0.f};

    const bf16x8 zfrag = {};
    size_t aoff = (size_t)arow * 64 + q * 4;

    bf16x8 aL[4], aX[4], aS[4];
#pragma unroll
    for (int ks = 0; ks < 4; ks++) {
        aL[ks] = rowOK ? *(const bf16x8*)(B1b + aoff + ks * 16) : zfrag;
        aX[ks] = rowOK ? *(const bf16x8*)(Xb  + aoff + ks * 16) : zfrag;
        aS[ks] = rowOK ? *(const bf16x8*)(B2b + aoff + ks * 16) : zfrag;
    }

#pragma unroll
    for (int ks = 0; ks < 4; ks++) {
#pragma unroll
        for (int nt = 0; nt < 5; nt++) {
            int boff = (nt * 16 + colLocal) * WSTRIDE + ks * 16 + q * 4;
            bf16x8 bW  = *(const bf16x8*)(sW  + boff);
            bf16x8 bWi = *(const bf16x8*)(sWi + boff);
            acc[nt] = __builtin_amdgcn_mfma_f32_16x16x32_bf16(aL[ks], bW,  acc[nt], 0, 0, 0);
            acc[nt] = __builtin_amdgcn_mfma_f32_16x16x32_bf16(aX[ks], bW,  acc[nt], 0, 0, 0);
            acc[nt] = __builtin_amdgcn_mfma_f32_16x16x32_bf16(aS[ks], bWi, acc[nt], 0, 0, 0);
        }
    }

    int sm[4];
    bool rok[4];
#pragma unroll
    for (int reg = 0; reg < 4; reg++) {
        int row = rowBase + q * 4 + reg;
        rok[reg] = row < N;
        sm[reg] = rok[reg] ? selMap[row] : -1;
    }
#pragma unroll
    for (int nt = 0; nt < 5; nt++) {
        int col = nt * 16 + colLocal;
        float bias = b[col] + bi[col];
#pragma unroll
        for (int reg = 0; reg < 4; reg++) {
            if (!rok[reg]) continue;
            int row = rowBase + q * 4 + reg;
            float v = fmaxf(acc[nt][reg] + bias, 0.f);
            F1b[(size_t)row * 80 + col] = cvt_bf16(v);
            if (sm[reg] >= 0) F1sel[(size_t)sm[reg] * 80 + col] = v;
        }
    }
}

// Layer-2 fused GEMM restricted to sampled rows; compact inputs.
__global__ __launch_bounds__(256) void gemm_fused2_sel(
    const float* __restrict__ Lxsel, const float* __restrict__ F1sel,
    const int* __restrict__ selMap,
    const float* __restrict__ S2c,
    const float* __restrict__ W, const float* __restrict__ b,
    const float* __restrict__ Wi, const float* __restrict__ bi,
    const int* __restrict__ userIdx, const int* __restrict__ itemIdx,
    float* __restrict__ outC)
{
    constexpr int K = 80, M = 50, TPR = 2, MT = M / TPR;
    __shared__ float sW[K * M];
    __shared__ float sWi[K * M];
    for (int i = threadIdx.x; i < K * M; i += 256) {
        sW[i]  = W[i];
        sWi[i] = Wi[i];
    }
    __syncthreads();

    int i = blockIdx.x * (256 / TPR) + (int)threadIdx.x / TPR;
    int mBase = ((int)threadIdx.x % TPR) * MT;
    if (i >= 2 * BATCH) return;
    int r = (i < BATCH) ? userIdx[i] : itemIdx[i - BATCH];
    int sm = selMap[r];

    const float* xrow = F1sel + (size_t)sm * K;
    const float* lrow = Lxsel + (size_t)sm * K;
    const float* srow = S2c + (size_t)i * K;

    float acc[MT];
#pragma unroll
    for (int m = 0; m < MT; m++) acc[m] = 0.0f;

    for (int k4 = 0; k4 < K; k4 += 4) {
        float4 lv = *(const float4*)(lrow + k4);
        float4 xv = *(const float4*)(xrow + k4);
        float4 sv = *(const float4*)(srow + k4);
        float a[4] = {lv.x + xv.x, lv.y + xv.y, lv.z + xv.z, lv.w + xv.w};
        float s[4] = {sv.x, sv.y, sv.z, sv.w};
#pragma unroll
        for (int kk = 0; kk < 4; kk++) {
            const float* wk  = &sW[(k4 + kk) * M + mBase];
            const float* wik = &sWi[(k4 + kk) * M + mBase];
#pragma unroll
            for (int m = 0; m < MT; m++)
                acc[m] = fmaf(a[kk], wk[m], fmaf(s[kk], wik[m], acc[m]));
        }
    }

    float* orow = outC + (size_t)i * M + mBase;
#pragma unroll
    for (int m = 0; m < MT; m++)
        orow[m] = fmaxf(acc[m] + b[mBase + m] + bi[mBase + m], 0.0f);
}

// ------------- Plain MLP GEMM ---------------------------------------------
template<int K, int M, int TPR, bool RELU>
__global__ __launch_bounds__(256) void mlp_gemm(
    const float* __restrict__ A,
    const float* __restrict__ W, const float* __restrict__ b,
    float* __restrict__ out, int N)
{
    __shared__ float sW[K * M];
    for (int i = threadIdx.x; i < K * M; i += 256) sW[i] = W[i];
    __syncthreads();

    constexpr int RPB = 256 / TPR;
    constexpr int MT  = M / TPR;
    int r = blockIdx.x * RPB + (int)threadIdx.x / TPR;
    int mBase = ((int)threadIdx.x % TPR) * MT;
    if (r >= N) return;

    const float* arow = A + (size_t)r * K;
    float acc[MT];
#pragma unroll
    for (int m = 0; m < MT; m++) acc[m] = 0.0f;

    for (int k = 0; k < K; k++) {
        float a = arow[k];
#pragma unroll
        for (int m = 0; m < MT; m++)
            acc[m] = fmaf(a, sW[k * M + mBase + m], acc[m]);
    }

    float* orow = out + (size_t)r * M + mBase;
#pragma unroll
    for (int m = 0; m < MT; m++) {
        float vv = acc[m] + b[mBase + m];
        orow[m] = RELU ? fmaxf(vv, 0.0f) : vv;
    }
}

// ------------- Gather final embeddings into [BATCH, 460] ------------------
__global__ __launch_bounds__(128) void gather_embd(
    const int* __restrict__ userIdx, const int* __restrict__ itemIdx,
    const float* __restrict__ uE, const float* __restrict__ iE,
    const float* __restrict__ F1sel, const int* __restrict__ selMap,
    const float* __restrict__ f2c,
    float* __restrict__ emb)
{
    int bi = blockIdx.x;
    int u  = userIdx[bi];
    int it = itemIdx[bi];
    int su = selMap[u];
    int si = selMap[it];
    float* orow = emb + (size_t)bi * 460;
    for (int c = threadIdx.x; c < 460; c += 128) {
        float val;
        if (c < 100) {
            val = (u < N_USERS) ? uE[(size_t)u * 100 + c]
                                : iE[(size_t)(u - N_USERS) * 100 + c];
        } else if (c < 180) {
            val = F1sel[(size_t)su * 80 + (c - 100)];
        } else if (c < 230) {
            val = f2c[(size_t)bi * 50 + (c - 180)];
        } else if (c < 330) {
            int cc = c - 230;
            val = (it < N_USERS) ? uE[(size_t)it * 100 + cc]
                                 : iE[(size_t)(it - N_USERS) * 100 + cc];
        } else if (c < 410) {
            val = F1sel[(size_t)si * 80 + (c - 330)];
        } else {
            val = f2c[(size_t)(BATCH + bi) * 50 + (c - 410)];
        }
        orow[c] = val;
    }
}

extern "C" void kernel_launch(void* const* d_in, const int* in_sizes, int n_in,
                              void* d_out, int out_size, void* d_ws, size_t ws_size,
                              hipStream_t stream) {
    const int*   userIdx = (const int*)d_in[0];
    const int*   itemIdx = (const int*)d_in[1];
    const int*   rows    = (const int*)d_in[2];
    const int*   cols    = (const int*)d_in[3];
    const float* vals    = (const float*)d_in[4];
    const float* uEmbd   = (const float*)d_in[5];
    const float* iEmbd   = (const float*)d_in[6];
    const float* w1      = (const float*)d_in[7];
    const float* b1      = (const float*)d_in[8];
    const float* wi1     = (const float*)d_in[9];
    const float* bi1     = (const float*)d_in[10];
    const float* w2      = (const float*)d_in[11];
    const float* b2      = (const float*)d_in[12];
    const float* wi2     = (const float*)d_in[13];
    const float* bi2     = (const float*)d_in[14];
    const float* t1w     = (const float*)d_in[15];
    const float* t1b     = (const float*)d_in[16];
    const float* t2w     = (const float*)d_in[17];
    const float* t2b     = (const float*)d_in[18];
    const float* t3w     = (const float*)d_in[19];
    const float* t3b     = (const float*)d_in[20];

    // ---- workspace layout (4-byte units) ----
    float* ws = (float*)d_ws;
    uint*  Xb64  = (uint*)ws;                  //  9,600,000 (MFMA A-stream)
    uint*  Xf8   = (uint*)(ws + 9600000);      //  4,800,000 (fp8 gather src, 128 B/row)
    uint*  B1b   = (uint*)(ws + 14400000);     //  9,600,000 (stride 64)
    uint*  Lxb   = B1b;                        //  6,000,000 alias (B1b dead after gemm1)
    uint*  INTf8 = (uint*)(ws + 24000000);     //  4,800,000 (fp8, 128 B/row)
    uint*  F1b   = (uint*)(ws + 28800000);     //  6,000,000 (bf16 stride 40)
    uint*  B2b   = (uint*)(ws + 34800000);     //  9,600,000 (stride 64)
    uint*  wtW   = (uint*)(ws + 44400000);     //      5,120
    uint*  wtWi  = (uint*)(ws + 44405120);     //      5,120
    float* F1sel = ws + 44410240;              //    655,360
    float* Lxsel = ws + 45065600;              //    655,360
    float* B2c   = ws + 45720960;              //    655,360
    float* F2c   = ws + 46376320;              //    409,600
    float* EMB   = ws + 46785920;              //  1,884,160
    float* H1    = ws + 48670080;              //    262,144
    float* H2    = ws + 48932224;              //    131,072
    int*   deg   = (int*)(ws + 49063296);      //    150,000
    int*   ptr   = deg + 150000;               //    150,000
    int*   pos   = ptr + 150000;               //    150,000
    int*   bsum  = pos + 150000;               //      1,024
    int2*  ep    = (int2*)(bsum + 1024);       //  1,500,096 int2 (EP_PAD)
    int*   flag  = (int*)(ep + 1500096);       //    150,000
    int*   selMap= flag + 150000;              //    150,000
    int*   sortedAll = selMap + 150000;        //    150,000
    int*   sorted3   = sortedAll + 150000;     //    150,000
    int*   blockHistT= sorted3 + 150000;       //     37,504 (NHIST, bin-major)
    int*   scanT     = blockHistT + NHIST;     //     37,504
    int*   bsum3     = scanT + NHIST;          //      1,024
    int*   cnt3      = bsum3 + 1024;           //          1   (~204 MB total)

    const int E = N_EDGES;
    dim3 blk(256);

    // ---- prep: bf16 + fp8 features, transposed bf16 weights ----
    cast_feats<<<(N_NODES * 64 + 255) / 256, blk, 0, stream>>>(uEmbd, iEmbd, Xb64);
    cast_fp8<<<(N_NODES * 32 + 255) / 256, blk, 0, stream>>>(uEmbd, iEmbd, Xf8);
    prep_weights<<<(2 * 80 * 64 + 255) / 256, blk, 0, stream>>>(w1, wi1, wtW, wtWi);

    // ---- CSR build ----
    hipMemsetAsync(deg, 0, 150000 * sizeof(int), stream);
    hipMemsetAsync(flag, 0, 150000 * sizeof(int), stream);
    hipMemsetAsync(selMap, 0xFF, 150000 * sizeof(int), stream);
    for (int s = 0; s < NSWEEP; s++) {
        hist_sweep<<<(E + 255) / 256, blk, 0, stream>>>(
            rows, deg, E, s * SWEEP_ROWS, (s + 1) * SWEEP_ROWS);
    }
    int nScanBlocks = NSB;                              // 586
    scan_block<<<nScanBlocks, blk, 0, stream>>>(deg, ptr, bsum, N_NODES);
    scan_tops<<<1, dim3(1024), 0, stream>>>(bsum, nScanBlocks);
    scan_apply<<<nScanBlocks, blk, 0, stream>>>(ptr, bsum, pos, N_NODES);
    for (int s = 0; s < NSWEEP; s++) {
        scatter_sweep<<<(E + 255) / 256, blk, 0, stream>>>(
            rows, cols, vals, pos, ep, E, s * SWEEP_ROWS, (s + 1) * SWEEP_ROWS);
    }
    pad_ep<<<1, dim3(128), 0, stream>>>(ep);

    // ---- selMap + needed-row marking ----
    build_selmap<<<(2 * BATCH + 255) / 256, blk, 0, stream>>>(userIdx, itemIdx, selMap);
    mark_needed<<<(2 * BATCH + 3) / 4, blk, 0, stream>>>(
        userIdx, itemIdx, ptr, deg, ep, flag);

    // ---- degree bucket sorts (bin-major hist + flat parallel scan) ----
    int nHistBlocks = (NHIST + 255) / 256;              // 147
    deg_hist_blk<<<nScanBlocks, blk, 0, stream>>>(deg, nullptr, blockHistT, N_NODES);
    scan_block<<<nHistBlocks, blk, 0, stream>>>(blockHistT, scanT, bsum3, NHIST);
    scan_tops<<<1, dim3(1024), 0, stream>>>(bsum3, nHistBlocks);
    scan_apply_tot<<<nHistBlocks, blk, 0, stream>>>(scanT, bsum3, blockHistT, nullptr, NHIST);
    deg_scatter_blk<<<nScanBlocks, blk, 0, stream>>>(deg, nullptr, scanT, sortedAll, N_NODES);
    deg_hist_blk<<<nScanBlocks, blk, 0, stream>>>(deg, flag, blockHistT, N_NODES);
    scan_block<<<nHistBlocks, blk, 0, stream>>>(blockHistT, scanT, bsum3, NHIST);
    scan_tops<<<1, dim3(1024), 0, stream>>>(bsum3, nHistBlocks);
    scan_apply_tot<<<nHistBlocks, blk, 0, stream>>>(scanT, bsum3, blockHistT, cnt3, NHIST);
    deg_scatter_blk<<<nScanBlocks, blk, 0, stream>>>(deg, flag, scanT, sorted3, N_NODES);

    int grpGrid8 = (N_NODES + 31) / 32;       // 32 rows per block (8-lane groups)
    int grpGrid  = (N_NODES + 15) / 16;       // 16 rows per block (16-lane groups)
    int selGrid  = (2 * BATCH + 3) / 4;

    // ---- Layer 1 (F = 100) ----
    spmm_pass1<<<grpGrid8, blk, 0, stream>>>(
        sortedAll, ptr, deg, ep, Xf8, B1b, INTf8, N_NODES);
    spmm_pass2<<<grpGrid8, blk, 0, stream>>>(
        sortedAll, ptr, deg, ep, INTf8, B2b, N_NODES);
    {
        int grid = (N_NODES + 63) / 64;
        gemm1_mfma<<<grid, blk, 0, stream>>>(
            B1b, Xb64, B2b, wtW, wtWi, b1, bi1, selMap,
            (ushort_t*)F1b, F1sel, N_NODES);
    }

    // ---- Layer 2 (F = 80) ----
    spmm_pass3<<<grpGrid, blk, 0, stream>>>(
        sorted3, cnt3, ptr, deg, ep, F1b, selMap, Lxb, Lxsel);
    spmm_pass4<<<selGrid, blk, 0, stream>>>(
        ptr, deg, ep, Lxb, F1b, userIdx, itemIdx, B2c);
    {
        int grid = (2 * BATCH + 127) / 128;
        gemm_fused2_sel<<<grid, blk, 0, stream>>>(
            Lxsel, F1sel, selMap, B2c, w2, b2, wi2, bi2, userIdx, itemIdx, F2c);
    }

    // ---- Gather + MLP ----
    gather_embd<<<BATCH, dim3(128), 0, stream>>>(
        userIdx, itemIdx, uEmbd, iEmbd, F1sel, selMap, F2c, EMB);
    {
        constexpr int TPR = 8;
        int grid = (BATCH + (256 / TPR) - 1) / (256 / TPR);
        mlp_gemm<460, 64, TPR, true><<<grid, blk, 0, stream>>>(
            EMB, t1w, t1b, H1, BATCH);
    }
    {
        constexpr int TPR = 4;
        int grid = (BATCH + (256 / TPR) - 1) / (256 / TPR);
        mlp_gemm<64, 32, TPR, false><<<grid, blk, 0, stream>>>(
            H1, t2w, t2b, H2, BATCH);
    }
    {
        constexpr int TPR = 1;
        int grid = (BATCH + 255) / 256;
        mlp_gemm<32, 1, TPR, false><<<grid, blk, 0, stream>>>(
            H2, t3w, t3b, (float*)d_out, BATCH);
    }
}

// Round 17
// 472.472 us; speedup vs baseline: 1.0161x; 1.0161x over previous
//
#include <hip/hip_runtime.h>

typedef unsigned int uint;
typedef unsigned short ushort_t;
typedef __attribute__((ext_vector_type(4))) float f32x4;
typedef __attribute__((ext_vector_type(2))) float f32x2;
typedef __attribute__((ext_vector_type(8))) short bf16x8;

#define N_USERS 100000
#define N_ITEMS 50000
#define N_NODES 150000
#define N_EDGES 1500000
#define BATCH 4096
#define NSWEEP 4
#define SWEEP_ROWS 37500
#define EP_PAD 96
#define NSB 586              // scan blocks over N_NODES
#define NHIST (NSB * 64)     // 37504
#define WSTRIDE 68           // LDS weight stride (uints): 16B-aligned, 2-way banks

__device__ __forceinline__ uint pack_bf16x2(float a, float b) {
    uint ua = __float_as_uint(a);
    uint ub = __float_as_uint(b);
    ua = (ua + 0x7FFFu + ((ua >> 16) & 1u)) >> 16;
    ub = (ub + 0x7FFFu + ((ub >> 16) & 1u)) >> 16;
    return ua | (ub << 16);
}
__device__ __forceinline__ ushort_t cvt_bf16(float a) {
    uint ua = __float_as_uint(a);
    return (ushort_t)((ua + 0x7FFFu + ((ua >> 16) & 1u)) >> 16);
}
__device__ __forceinline__ float bf_lo(uint u) { return __uint_as_float(u << 16); }
__device__ __forceinline__ float bf_hi(uint u) { return __uint_as_float(u & 0xFFFF0000u); }

// fp8 e4m3 pack/unpack (HW cvt, 2 elems per inst)
__device__ __forceinline__ uint pack_fp8x4(float a, float b, float c, float d) {
    uint r = 0;
    r = (uint)__builtin_amdgcn_cvt_pk_fp8_f32(a, b, (int)r, false);
    r = (uint)__builtin_amdgcn_cvt_pk_fp8_f32(c, d, (int)r, true);
    return r;
}
__device__ __forceinline__ void unpack_fp8x4(uint u, float o[4]) {
    f32x2 lo = __builtin_amdgcn_cvt_pk_f32_fp8((int)u, false);
    f32x2 hi = __builtin_amdgcn_cvt_pk_f32_fp8((int)u, true);
    o[0] = lo.x; o[1] = lo.y; o[2] = hi.x; o[3] = hi.y;
}

// ===== fp8 group gather: 8-lane group per row, lane l = uint4 (16 fp8) ======
__device__ __forceinline__ void gather8_fp8(
    const int2* __restrict__ ep, int st, int d,
    const uint4* __restrict__ s4, int l, float acc[16])
{
    int2 e0 = ep[st];
    int2 e1 = ep[st + 1];
    uint4 g0 = {0u, 0u, 0u, 0u};
    if (0 < d) g0 = s4[(size_t)(uint)e0.x * 8 + l];
    for (int j = 0; j < d; j++) {
        int2 e2 = ep[st + j + 2];
        uint4 g1 = {0u, 0u, 0u, 0u};
        if (j + 1 < d) g1 = s4[(size_t)(uint)e1.x * 8 + l];
        float v = __int_as_float(e0.y);
        float f[4];
        unpack_fp8x4(g0.x, f);
#pragma unroll
        for (int k = 0; k < 4; k++) acc[k]      = fmaf(v, f[k], acc[k]);
        unpack_fp8x4(g0.y, f);
#pragma unroll
        for (int k = 0; k < 4; k++) acc[4 + k]  = fmaf(v, f[k], acc[4 + k]);
        unpack_fp8x4(g0.z, f);
#pragma unroll
        for (int k = 0; k < 4; k++) acc[8 + k]  = fmaf(v, f[k], acc[8 + k]);
        unpack_fp8x4(g0.w, f);
#pragma unroll
        for (int k = 0; k < 4; k++) acc[12 + k] = fmaf(v, f[k], acc[12 + k]);
        e0 = e1; e1 = e2; g0 = g1;
    }
}

// ===== bf16 group gather (pass3): 16-lane group, lane l gathers uint4 ======
template<int PU4>
__device__ __forceinline__ void group_gather(
    const int2* __restrict__ ep, int st, int d, int dmax,
    const uint* __restrict__ src, int l,
    float aLo[4], float aHi[4])
{
    const uint4* s4 = (const uint4*)src;
    bool lok = l < PU4;
    int2 e0 = ep[st];
    int2 e1 = ep[st + 1];
    uint4 g0 = {0u, 0u, 0u, 0u};
    if (lok && 0 < d) g0 = s4[(size_t)(uint)e0.x * PU4 + l];
    for (int j = 0; j < dmax; j++) {
        int2 e2 = ep[st + j + 2];
        uint4 g1 = {0u, 0u, 0u, 0u};
        if (lok && j + 1 < d) g1 = s4[(size_t)(uint)e1.x * PU4 + l];
        float v = (j < d) ? __int_as_float(e0.y) : 0.f;
        aLo[0] = fmaf(v, bf_lo(g0.x), aLo[0]); aHi[0] = fmaf(v, bf_hi(g0.x), aHi[0]);
        aLo[1] = fmaf(v, bf_lo(g0.y), aLo[1]); aHi[1] = fmaf(v, bf_hi(g0.y), aHi[1]);
        aLo[2] = fmaf(v, bf_lo(g0.z), aLo[2]); aHi[2] = fmaf(v, bf_hi(g0.z), aHi[2]);
        aLo[3] = fmaf(v, bf_lo(g0.w), aLo[3]); aHi[3] = fmaf(v, bf_hi(g0.w), aHi[3]);
        e0 = e1; e1 = e2; g0 = g1;
    }
}

// Dual-stream 4-deep per-row variant for pass4 (small): P = 40 uints
__device__ __forceinline__ float2 row_gather_accum_mul(
    const int2* __restrict__ ep, int st, int d,
    const uint* __restrict__ sA, const uint* __restrict__ sB, int lane)
{
    constexpr int P = 40;
    float ax = 0.f, ay = 0.f;
    bool lok = lane < P;
    int2 e0 = ep[st],     e1 = ep[st + 1], e2 = ep[st + 2], e3 = ep[st + 3];
    int2 e4 = ep[st + 4], e5 = ep[st + 5];
    uint a0 = (lok && 0 < d) ? sA[(size_t)e0.x * P + lane] : 0u;
    uint c0 = (lok && 0 < d) ? sB[(size_t)e0.x * P + lane] : 0u;
    uint a1 = (lok && 1 < d) ? sA[(size_t)e1.x * P + lane] : 0u;
    uint c1 = (lok && 1 < d) ? sB[(size_t)e1.x * P + lane] : 0u;
    uint a2 = (lok && 2 < d) ? sA[(size_t)e2.x * P + lane] : 0u;
    uint c2 = (lok && 2 < d) ? sB[(size_t)e2.x * P + lane] : 0u;
    uint a3 = (lok && 3 < d) ? sA[(size_t)e3.x * P + lane] : 0u;
    uint c3 = (lok && 3 < d) ? sB[(size_t)e3.x * P + lane] : 0u;
    for (int j = 0; j < d; j += 2) {
        uint nA4 = (lok && j + 4 < d) ? sA[(size_t)e4.x * P + lane] : 0u;
        uint nC4 = (lok && j + 4 < d) ? sB[(size_t)e4.x * P + lane] : 0u;
        uint nA5 = (lok && j + 5 < d) ? sA[(size_t)e5.x * P + lane] : 0u;
        uint nC5 = (lok && j + 5 < d) ? sB[(size_t)e5.x * P + lane] : 0u;
        int2 n6 = ep[st + j + 6];
        int2 n7 = ep[st + j + 7];
        float v0 = __int_as_float(e0.y);
        ax = fmaf(v0, bf_lo(a0) * bf_lo(c0), ax);
        ay = fmaf(v0, bf_hi(a0) * bf_hi(c0), ay);
        if (j + 1 < d) {
            float v1 = __int_as_float(e1.y);
            ax = fmaf(v1, bf_lo(a1) * bf_lo(c1), ax);
            ay = fmaf(v1, bf_hi(a1) * bf_hi(c1), ay);
        }
        e0 = e2; a0 = a2; c0 = c2; e1 = e3; a1 = a3; c1 = c3;
        e2 = e4; a2 = nA4; c2 = nC4; e3 = e5; a3 = nA5; c3 = nC5;
        e4 = n6; e5 = n7;
    }
    return make_float2(ax, ay);
}

// ============ bf16 feature cast: Xb64 (MFMA A-stream, stride 64 uints) ========
__global__ __launch_bounds__(256) void cast_feats(
    const float* __restrict__ uE, const float* __restrict__ iE,
    uint* __restrict__ Xb64)
{
    int g = blockIdx.x * 256 + threadIdx.x;
    if (g >= N_NODES * 64) return;
    int row = g >> 6, c = g & 63;
    uint outv = 0u;
    if (c < 50) {
        int e0 = c * 2;
        float a, b;
        if (row < N_USERS) { a = uE[(size_t)row * 100 + e0]; b = uE[(size_t)row * 100 + e0 + 1]; }
        else { a = iE[(size_t)(row - N_USERS) * 100 + e0]; b = iE[(size_t)(row - N_USERS) * 100 + e0 + 1]; }
        outv = pack_bf16x2(a, b);
    }
    Xb64[g] = outv;
}

// ============ fp8 feature cast: Xf8 = fp8(16*x), stride 32 uints (128 B) ======
__global__ __launch_bounds__(256) void cast_fp8(
    const float* __restrict__ uE, const float* __restrict__ iE,
    uint* __restrict__ Xf8)
{
    int g = blockIdx.x * 256 + threadIdx.x;
    if (g >= N_NODES * 32) return;
    int row = g >> 5, c = g & 31;
    uint outv = 0u;
    int f0 = c * 4;
    if (f0 < 100) {
        const float* src = (row < N_USERS) ? (uE + (size_t)row * 100)
                                           : (iE + (size_t)(row - N_USERS) * 100);
        outv = pack_fp8x4(src[f0] * 16.f, src[f0 + 1] * 16.f,
                          src[f0 + 2] * 16.f, src[f0 + 3] * 16.f);
    }
    Xf8[g] = outv;
}

// ============ weight prep: wT bf16 [80 cols][64 uints=128 k, zero-padded] =====
__global__ __launch_bounds__(256) void prep_weights(
    const float* __restrict__ W, const float* __restrict__ Wi,
    uint* __restrict__ wtW, uint* __restrict__ wtWi)
{
    int t = blockIdx.x * 256 + threadIdx.x;
    if (t >= 2 * 80 * 64) return;
    const float* src = (t < 80 * 64) ? W : Wi;
    uint* dst = (t < 80 * 64) ? wtW : wtWi;
    int i = t % (80 * 64);
    int col = i >> 6, kk = i & 63;
    int k = kk * 2;
    uint v = 0u;
    if (k < 100) v = pack_bf16x2(src[(size_t)k * 80 + col], src[(size_t)(k + 1) * 80 + col]);
    dst[(size_t)col * 64 + kk] = v;
}

// ======================= CSR construction =======================
__global__ __launch_bounds__(256) void hist_kernel(
    const int* __restrict__ rows, int* __restrict__ deg, int E)
{
    int e = blockIdx.x * 256 + threadIdx.x;
    if (e < E) atomicAdd(&deg[rows[e]], 1);
}

__global__ __launch_bounds__(256) void scan_block(
    const int* __restrict__ deg, int* __restrict__ ptr,
    int* __restrict__ bsum, int n)
{
    __shared__ int s[256];
    int t = threadIdx.x;
    int i = blockIdx.x * 256 + t;
    int v = (i < n) ? deg[i] : 0;
    s[t] = v; __syncthreads();
    for (int off = 1; off < 256; off <<= 1) {
        int x = (t >= off) ? s[t - off] : 0;
        __syncthreads();
        s[t] += x;
        __syncthreads();
    }
    if (i < n) ptr[i] = s[t] - v;
    if (t == 255) bsum[blockIdx.x] = s[255];
}

__global__ __launch_bounds__(1024) void scan_tops(int* __restrict__ bsum, int nb)
{
    __shared__ int s[1024];
    int t = threadIdx.x;
    int v = (t < nb) ? bsum[t] : 0;
    s[t] = v; __syncthreads();
    for (int off = 1; off < 1024; off <<= 1) {
        int x = (t >= off) ? s[t - off] : 0;
        __syncthreads();
        s[t] += x;
        __syncthreads();
    }
    if (t < nb) bsum[t] = s[t] - v;
}

__global__ __launch_bounds__(256) void scan_apply(
    int* __restrict__ ptr, const int* __restrict__ bsum,
    int* __restrict__ pos, int n)
{
    int i = blockIdx.x * 256 + threadIdx.x;
    if (i < n) {
        int p = ptr[i] + bsum[i >> 8];
        ptr[i] = p;
        pos[i] = p;
    }
}

// scan finalize (in place) + optional grand total
__global__ __launch_bounds__(256) void scan_apply_tot(
    int* __restrict__ scanT, const int* __restrict__ bsum,
    const int* __restrict__ orig, int* __restrict__ total, int n)
{
    int i = blockIdx.x * 256 + threadIdx.x;
    if (i < n) {
        int p = scanT[i] + bsum[i >> 8];
        scanT[i] = p;
        if (total && i == n - 1) *total = p + orig[i];
    }
}

// Swept scatter: L2-resident ep window per sweep kills HBM write amplification.
__global__ __launch_bounds__(256) void scatter_sweep(
    const int* __restrict__ rows, const int* __restrict__ cols,
    const float* __restrict__ vals, int* __restrict__ pos,
    int2* __restrict__ ep, int E, int lo, int hi)
{
    int e = blockIdx.x * 256 + threadIdx.x;
    if (e >= E) return;
    int r = rows[e];
    if (r < lo || r >= hi) return;
    int p = atomicAdd(&pos[r], 1);
    ep[p] = make_int2(cols[e], __float_as_int(vals[e]));
}

__global__ __launch_bounds__(128) void pad_ep(int2* __restrict__ ep)
{
    int t = threadIdx.x;
    if (t < EP_PAD) ep[N_EDGES + t] = make_int2(0, 0);
}

// ============== selMap + needed-row marking =====================
__global__ __launch_bounds__(256) void build_selmap(
    const int* __restrict__ userIdx, const int* __restrict__ itemIdx,
    int* __restrict__ selMap)
{
    int i = blockIdx.x * 256 + threadIdx.x;
    if (i < BATCH) selMap[userIdx[i]] = i;
    else if (i < 2 * BATCH) selMap[itemIdx[i - BATCH]] = i;
}

__global__ __launch_bounds__(256) void mark_needed(
    const int* __restrict__ userIdx, const int* __restrict__ itemIdx,
    const int* __restrict__ ptr_, const int* __restrict__ deg_,
    const int2* __restrict__ ep, int* __restrict__ flag)
{
    int i = blockIdx.x * 4 + ((int)threadIdx.x >> 6);
    if (i >= 2 * BATCH) return;
    int lane = threadIdx.x & 63;
    int row = (i < BATCH) ? userIdx[i] : itemIdx[i - BATCH];
    if (lane == 0) flag[row] = 1;
    int st = ptr_[row], d = deg_[row];
    for (int j = lane; j < d; j += 64)
        flag[ep[st + j].x] = 1;
}

// ========= degree bucket sort: LDS hist (bin-major) + flat parallel scan ======
__global__ __launch_bounds__(256) void deg_hist_blk(
    const int* __restrict__ deg, const int* __restrict__ flag,
    int* __restrict__ blockHistT, int n)
{
    __shared__ int h[64];
    int t = threadIdx.x;
    if (t < 64) h[t] = 0;
    __syncthreads();
    int i = blockIdx.x * 256 + t;
    if (i < n && (!flag || flag[i])) {
        int b = deg[i]; if (b > 63) b = 63;
        atomicAdd(&h[b], 1);
    }
    __syncthreads();
    if (t < 64) blockHistT[t * NSB + blockIdx.x] = h[t];
}

__global__ __launch_bounds__(256) void deg_scatter_blk(
    const int* __restrict__ deg, const int* __restrict__ flag,
    const int* __restrict__ scanT, int* __restrict__ sorted, int n)
{
    __shared__ int cnt[64];
    __shared__ int base[64];
    int t = threadIdx.x;
    if (t < 64) { cnt[t] = 0; base[t] = scanT[t * NSB + blockIdx.x]; }
    __syncthreads();
    int i = blockIdx.x * 256 + t;
    if (i < n && (!flag || flag[i])) {
        int b = deg[i]; if (b > 63) b = 63;
        int loc = atomicAdd(&cnt[b], 1);
        sorted[base[b] + loc] = i;
    }
}

// =========== SpMM pass1/pass2: 8-lane groups, fp8 sources, deg-sorted =========

// Pass 1: B1b64 = bf16(L@X); INTf8 = fp8(4096*(L@X .* X))
__global__ __launch_bounds__(256) void spmm_pass1(
    const int* __restrict__ sortedAll,
    const int* __restrict__ ptr_, const int* __restrict__ deg_,
    const int2* __restrict__ ep, const uint* __restrict__ Xf8,
    uint* __restrict__ B1b, uint* __restrict__ INTf8, int N)
{
    int wave = (int)threadIdx.x >> 6, lane = (int)threadIdx.x & 63;
    int grp = lane >> 3, l = lane & 7;
    int si = blockIdx.x * 32 + wave * 8 + grp;
    bool valid = si < N;
    int row = valid ? sortedAll[si] : 0;
    int d = valid ? deg_[row] : 0;
    int st = valid ? ptr_[row] : 0;
    float acc[16];
#pragma unroll
    for (int k = 0; k < 16; k++) acc[k] = 0.f;
    gather8_fp8(ep, st, d, (const uint4*)Xf8, l, acc);
    if (!valid) return;

    uint u[8];
#pragma unroll
    for (int k = 0; k < 8; k++)
        u[k] = pack_bf16x2(acc[2 * k] * 0.0625f, acc[2 * k + 1] * 0.0625f);
    uint4* bdst = (uint4*)(B1b + (size_t)row * 64 + l * 8);
    bdst[0] = make_uint4(u[0], u[1], u[2], u[3]);
    bdst[1] = make_uint4(u[4], u[5], u[6], u[7]);

    uint4 xs4 = ((const uint4*)(Xf8 + (size_t)row * 32))[l];
    float xs[16];
    unpack_fp8x4(xs4.x, xs); unpack_fp8x4(xs4.y, xs + 4);
    unpack_fp8x4(xs4.z, xs + 8); unpack_fp8x4(xs4.w, xs + 12);
    float t[16];
#pragma unroll
    for (int k = 0; k < 16; k++) t[k] = 16.f * acc[k] * xs[k];
    uint4 o;
    o.x = pack_fp8x4(t[0], t[1], t[2], t[3]);
    o.y = pack_fp8x4(t[4], t[5], t[6], t[7]);
    o.z = pack_fp8x4(t[8], t[9], t[10], t[11]);
    o.w = pack_fp8x4(t[12], t[13], t[14], t[15]);
    ((uint4*)(INTf8 + (size_t)row * 32))[l] = o;
}

// Pass 2: B2b64 = bf16(L @ INT)  (INTf8 stores 4096*INT -> descale at output)
__global__ __launch_bounds__(256) void spmm_pass2(
    const int* __restrict__ sortedAll,
    const int* __restrict__ ptr_, const int* __restrict__ deg_,
    const int2* __restrict__ ep, const uint* __restrict__ INTf8,
    uint* __restrict__ B2b, int N)
{
    int wave = (int)threadIdx.x >> 6, lane = (int)threadIdx.x & 63;
    int grp = lane >> 3, l = lane & 7;
    int si = blockIdx.x * 32 + wave * 8 + grp;
    bool valid = si < N;
    int row = valid ? sortedAll[si] : 0;
    int d = valid ? deg_[row] : 0;
    int st = valid ? ptr_[row] : 0;
    float acc[16];
#pragma unroll
    for (int k = 0; k < 16; k++) acc[k] = 0.f;
    gather8_fp8(ep, st, d, (const uint4*)INTf8, l, acc);
    if (!valid) return;
    const float DS = 1.f / 4096.f;
    uint u[8];
#pragma unroll
    for (int k = 0; k < 8; k++)
        u[k] = pack_bf16x2(acc[2 * k] * DS, acc[2 * k + 1] * DS);
    uint4* bdst = (uint4*)(B2b + (size_t)row * 64 + l * 8);
    bdst[0] = make_uint4(u[0], u[1], u[2], u[3]);
    bdst[1] = make_uint4(u[4], u[5], u[6], u[7]);
}

// Pass 3: Lx2 = L@F1 over deg-sorted needed list; bf16 Lxb40 + fp32 Lxsel
__global__ __launch_bounds__(256) void spmm_pass3(
    const int* __restrict__ sorted3, const int* __restrict__ cnt3,
    const int* __restrict__ ptr_, const int* __restrict__ deg_,
    const int2* __restrict__ ep, const uint* __restrict__ F1b,
    const int* __restrict__ selMap,
    uint* __restrict__ Lxb, float* __restrict__ Lxsel)
{
    int wave = (int)threadIdx.x >> 6, lane = (int)threadIdx.x & 63;
    int grp = lane >> 4, l = lane & 15;
    int si = blockIdx.x * 16 + wave * 4 + grp;
    int n3 = *cnt3;
    bool valid = si < n3;
    int row = valid ? sorted3[si] : 0;
    int d = valid ? deg_[row] : 0;
    int st = valid ? ptr_[row] : 0;
    int dm = d, t;
    t = __shfl_xor(dm, 16); dm = dm > t ? dm : t;
    t = __shfl_xor(dm, 32); dm = dm > t ? dm : t;
    float aLo[4] = {0.f, 0.f, 0.f, 0.f}, aHi[4] = {0.f, 0.f, 0.f, 0.f};
    group_gather<10>(ep, st, d, dm, F1b, l, aLo, aHi);
    if (!valid || l >= 10) return;
    uint4 o;
    o.x = pack_bf16x2(aLo[0], aHi[0]); o.y = pack_bf16x2(aLo[1], aHi[1]);
    o.z = pack_bf16x2(aLo[2], aHi[2]); o.w = pack_bf16x2(aLo[3], aHi[3]);
    ((uint4*)(Lxb + (size_t)row * 40))[l] = o;
    int sm = selMap[row];
    if (sm >= 0) {
        float4 f0 = make_float4(aLo[0], aHi[0], aLo[1], aHi[1]);
        float4 f1 = make_float4(aLo[2], aHi[2], aLo[3], aHi[3]);
        ((float4*)(Lxsel + (size_t)sm * 80))[2 * l]     = f0;
        ((float4*)(Lxsel + (size_t)sm * 80))[2 * l + 1] = f1;
    }
}

// Pass 4 (selected rows): B2c[i] = sum_e v * (Lx2[c] .* F1[c]), both bf16
__global__ __launch_bounds__(256) void spmm_pass4(
    const int* __restrict__ ptr_, const int* __restrict__ deg_,
    const int2* __restrict__ ep,
    const uint* __restrict__ Lxb, const uint* __restrict__ F1b,
    const int* __restrict__ userIdx, const int* __restrict__ itemIdx,
    float* __restrict__ outC)
{
    int i = blockIdx.x * 4 + ((int)threadIdx.x >> 6);
    if (i >= 2 * BATCH) return;
    int row = (i < BATCH) ? userIdx[i] : itemIdx[i - BATCH];
    int lane = threadIdx.x & 63;
    float2 r = row_gather_accum_mul(ep, ptr_[row], deg_[row], Lxb, F1b, lane);
    if (lane < 40)
        ((float2*)(outC + (size_t)i * 80))[lane] = r;
}

// ------------- Layer-1 fused linear via MFMA, weights in LDS ----------------
__global__ __launch_bounds__(256) void gemm1_mfma(
    const uint* __restrict__ B1b, const uint* __restrict__ Xb,
    const uint* __restrict__ B2b,
    const uint* __restrict__ wtW, const uint* __restrict__ wtWi,
    const float* __restrict__ b, const float* __restrict__ bi,
    const int* __restrict__ selMap,
    ushort_t* __restrict__ F1b, float* __restrict__ F1sel, int N)
{
    __shared__ uint sW[80 * WSTRIDE];
    __shared__ uint sWi[80 * WSTRIDE];
    for (int i = threadIdx.x; i < 80 * 64; i += 256) {
        int col = i >> 6, kk = i & 63;
        sW[col * WSTRIDE + kk]  = wtW[i];
        sWi[col * WSTRIDE + kk] = wtWi[i];
    }
    __syncthreads();

    int wave = (int)threadIdx.x >> 6;
    int lane = (int)threadIdx.x & 63;
    int rowBase = blockIdx.x * 64 + wave * 16;
    int colLocal = lane & 15;
    int q = lane >> 4;
    int arow = rowBase + colLocal;
    bool rowOK = arow < N;

    f32x4 acc[5];
#pragma unroll
    for (int nt = 0; nt < 5; nt++) acc[nt] = (f32x4){0.f, 0.f, 0.f, 0.f};

    const bf16x8 zfrag = {};
    size_t aoff = (size_t)arow * 64 + q * 4;

    bf16x8 aL[4], aX[4], aS[4];
#pragma unroll
    for (int ks = 0; ks < 4; ks++) {
        aL[ks] = rowOK ? *(const bf16x8*)(B1b + aoff + ks * 16) : zfrag;
        aX[ks] = rowOK ? *(const bf16x8*)(Xb  + aoff + ks * 16) : zfrag;
        aS[ks] = rowOK ? *(const bf16x8*)(B2b + aoff + ks * 16) : zfrag;
    }

#pragma unroll
    for (int ks = 0; ks < 4; ks++) {
#pragma unroll
        for (int nt = 0; nt < 5; nt++) {
            int boff = (nt * 16 + colLocal) * WSTRIDE + ks * 16 + q * 4;
            bf16x8 bW  = *(const bf16x8*)(sW  + boff);
            bf16x8 bWi = *(const bf16x8*)(sWi + boff);
            acc[nt] = __builtin_amdgcn_mfma_f32_16x16x32_bf16(aL[ks], bW,  acc[nt], 0, 0, 0);
            acc[nt] = __builtin_amdgcn_mfma_f32_16x16x32_bf16(aX[ks], bW,  acc[nt], 0, 0, 0);
            acc[nt] = __builtin_amdgcn_mfma_f32_16x16x32_bf16(aS[ks], bWi, acc[nt], 0, 0, 0);
        }
    }

    int sm[4];
    bool rok[4];
#pragma unroll
    for (int reg = 0; reg < 4; reg++) {
        int row = rowBase + q * 4 + reg;
        rok[reg] = row < N;
        sm[reg] = rok[reg] ? selMap[row] : -1;
    }
#pragma unroll
    for (int nt = 0; nt < 5; nt++) {
        int col = nt * 16 + colLocal;
        float bias = b[col] + bi[col];
#pragma unroll
        for (int reg = 0; reg < 4; reg++) {
            if (!rok[reg]) continue;
            int row = rowBase + q * 4 + reg;
            float v = fmaxf(acc[nt][reg] + bias, 0.f);
            F1b[(size_t)row * 80 + col] = cvt_bf16(v);
            if (sm[reg] >= 0) F1sel[(size_t)sm[reg] * 80 + col] = v;
        }
    }
}

// Layer-2 fused GEMM restricted to sampled rows; compact inputs.
__global__ __launch_bounds__(256) void gemm_fused2_sel(
    const float* __restrict__ Lxsel, const float* __restrict__ F1sel,
    const int* __restrict__ selMap,
    const float* __restrict__ S2c,
    const float* __restrict__ W, const float* __restrict__ b,
    const float* __restrict__ Wi, const float* __restrict__ bi,
    const int* __restrict__ userIdx, const int* __restrict__ itemIdx,
    float* __restrict__ outC)
{
    constexpr int K = 80, M = 50, TPR = 2, MT = M / TPR;
    __shared__ float sW[K * M];
    __shared__ float sWi[K * M];
    for (int i = threadIdx.x; i < K * M; i += 256) {
        sW[i]  = W[i];
        sWi[i] = Wi[i];
    }
    __syncthreads();

    int i = blockIdx.x * (256 / TPR) + (int)threadIdx.x / TPR;
    int mBase = ((int)threadIdx.x % TPR) * MT;
    if (i >= 2 * BATCH) return;
    int r = (i < BATCH) ? userIdx[i] : itemIdx[i - BATCH];
    int sm = selMap[r];

    const float* xrow = F1sel + (size_t)sm * K;
    const float* lrow = Lxsel + (size_t)sm * K;
    const float* srow = S2c + (size_t)i * K;

    float acc[MT];
#pragma unroll
    for (int m = 0; m < MT; m++) acc[m] = 0.0f;

    for (int k4 = 0; k4 < K; k4 += 4) {
        float4 lv = *(const float4*)(lrow + k4);
        float4 xv = *(const float4*)(xrow + k4);
        float4 sv = *(const float4*)(srow + k4);
        float a[4] = {lv.x + xv.x, lv.y + xv.y, lv.z + xv.z, lv.w + xv.w};
        float s[4] = {sv.x, sv.y, sv.z, sv.w};
#pragma unroll
        for (int kk = 0; kk < 4; kk++) {
            const float* wk  = &sW[(k4 + kk) * M + mBase];
            const float* wik = &sWi[(k4 + kk) * M + mBase];
#pragma unroll
            for (int m = 0; m < MT; m++)
                acc[m] = fmaf(a[kk], wk[m], fmaf(s[kk], wik[m], acc[m]));
        }
    }

    float* orow = outC + (size_t)i * M + mBase;
#pragma unroll
    for (int m = 0; m < MT; m++)
        orow[m] = fmaxf(acc[m] + b[mBase + m] + bi[mBase + m], 0.0f);
}

// ------------- Plain MLP GEMM ---------------------------------------------
template<int K, int M, int TPR, bool RELU>
__global__ __launch_bounds__(256) void mlp_gemm(
    const float* __restrict__ A,
    const float* __restrict__ W, const float* __restrict__ b,
    float* __restrict__ out, int N)
{
    __shared__ float sW[K * M];
    for (int i = threadIdx.x; i < K * M; i += 256) sW[i] = W[i];
    __syncthreads();

    constexpr int RPB = 256 / TPR;
    constexpr int MT  = M / TPR;
    int r = blockIdx.x * RPB + (int)threadIdx.x / TPR;
    int mBase = ((int)threadIdx.x % TPR) * MT;
    if (r >= N) return;

    const float* arow = A + (size_t)r * K;
    float acc[MT];
#pragma unroll
    for (int m = 0; m < MT; m++) acc[m] = 0.0f;

    for (int k = 0; k < K; k++) {
        float a = arow[k];
#pragma unroll
        for (int m = 0; m < MT; m++)
            acc[m] = fmaf(a, sW[k * M + mBase + m], acc[m]);
    }

    float* orow = out + (size_t)r * M + mBase;
#pragma unroll
    for (int m = 0; m < MT; m++) {
        float vv = acc[m] + b[mBase + m];
        orow[m] = RELU ? fmaxf(vv, 0.0f) : vv;
    }
}

// ------------- Gather final embeddings into [BATCH, 460] ------------------
__global__ __launch_bounds__(128) void gather_embd(
    const int* __restrict__ userIdx, const int* __restrict__ itemIdx,
    const float* __restrict__ uE, const float* __restrict__ iE,
    const float* __restrict__ F1sel, const int* __restrict__ selMap,
    const float* __restrict__ f2c,
    float* __restrict__ emb)
{
    int bi = blockIdx.x;
    int u  = userIdx[bi];
    int it = itemIdx[bi];
    int su = selMap[u];
    int si = selMap[it];
    float* orow = emb + (size_t)bi * 460;
    for (int c = threadIdx.x; c < 460; c += 128) {
        float val;
        if (c < 100) {
            val = (u < N_USERS) ? uE[(size_t)u * 100 + c]
                                : iE[(size_t)(u - N_USERS) * 100 + c];
        } else if (c < 180) {
            val = F1sel[(size_t)su * 80 + (c - 100)];
        } else if (c < 230) {
            val = f2c[(size_t)bi * 50 + (c - 180)];
        } else if (c < 330) {
            int cc = c - 230;
            val = (it < N_USERS) ? uE[(size_t)it * 100 + cc]
                                 : iE[(size_t)(it - N_USERS) * 100 + cc];
        } else if (c < 410) {
            val = F1sel[(size_t)si * 80 + (c - 330)];
        } else {
            val = f2c[(size_t)(BATCH + bi) * 50 + (c - 410)];
        }
        orow[c] = val;
    }
}

extern "C" void kernel_launch(void* const* d_in, const int* in_sizes, int n_in,
                              void* d_out, int out_size, void* d_ws, size_t ws_size,
                              hipStream_t stream) {
    const int*   userIdx = (const int*)d_in[0];
    const int*   itemIdx = (const int*)d_in[1];
    const int*   rows    = (const int*)d_in[2];
    const int*   cols    = (const int*)d_in[3];
    const float* vals    = (const float*)d_in[4];
    const float* uEmbd   = (const float*)d_in[5];
    const float* iEmbd   = (const float*)d_in[6];
    const float* w1      = (const float*)d_in[7];
    const float* b1      = (const float*)d_in[8];
    const float* wi1     = (const float*)d_in[9];
    const float* bi1     = (const float*)d_in[10];
    const float* w2      = (const float*)d_in[11];
    const float* b2      = (const float*)d_in[12];
    const float* wi2     = (const float*)d_in[13];
    const float* bi2     = (const float*)d_in[14];
    const float* t1w     = (const float*)d_in[15];
    const float* t1b     = (const float*)d_in[16];
    const float* t2w     = (const float*)d_in[17];
    const float* t2b     = (const float*)d_in[18];
    const float* t3w     = (const float*)d_in[19];
    const float* t3b     = (const float*)d_in[20];

    // ---- workspace layout (4-byte units) ----
    float* ws = (float*)d_ws;
    uint*  Xb64  = (uint*)ws;                  //  9,600,000 (MFMA A-stream)
    uint*  Xf8   = (uint*)(ws + 9600000);      //  4,800,000 (fp8 gather src, 128 B/row)
    uint*  B1b   = (uint*)(ws + 14400000);     //  9,600,000 (stride 64)
    uint*  Lxb   = B1b;                        //  6,000,000 alias (B1b dead after gemm1)
    uint*  INTf8 = (uint*)(ws + 24000000);     //  4,800,000 (fp8, 128 B/row)
    uint*  F1b   = (uint*)(ws + 28800000);     //  6,000,000 (bf16 stride 40)
    uint*  B2b   = (uint*)(ws + 34800000);     //  9,600,000 (stride 64)
    uint*  wtW   = (uint*)(ws + 44400000);     //      5,120
    uint*  wtWi  = (uint*)(ws + 44405120);     //      5,120
    float* F1sel = ws + 44410240;              //    655,360
    float* Lxsel = ws + 45065600;              //    655,360
    float* B2c   = ws + 45720960;              //    655,360
    float* F2c   = ws + 46376320;              //    409,600
    float* EMB   = ws + 46785920;              //  1,884,160
    float* H1    = ws + 48670080;              //    262,144
    float* H2    = ws + 48932224;              //    131,072
    int*   deg   = (int*)(ws + 49063296);      //    150,000
    int*   ptr   = deg + 150000;               //    150,000
    int*   pos   = ptr + 150000;               //    150,000
    int*   bsum  = pos + 150000;               //      1,024
    int2*  ep    = (int2*)(bsum + 1024);       //  1,500,096 int2 (EP_PAD)
    int*   flag  = (int*)(ep + 1500096);       //    150,000
    int*   selMap= flag + 150000;              //    150,000
    int*   sortedAll = selMap + 150000;        //    150,000
    int*   sorted3   = sortedAll + 150000;     //    150,000
    int*   blockHistT= sorted3 + 150000;       //     37,504 (NHIST, bin-major)
    int*   scanT     = blockHistT + NHIST;     //     37,504
    int*   bsum3     = scanT + NHIST;          //      1,024
    int*   cnt3      = bsum3 + 1024;           //          1   (~204 MB total)

    const int E = N_EDGES;
    dim3 blk(256);

    // ---- prep: bf16 + fp8 features, transposed bf16 weights ----
    cast_feats<<<(N_NODES * 64 + 255) / 256, blk, 0, stream>>>(uEmbd, iEmbd, Xb64);
    cast_fp8<<<(N_NODES * 32 + 255) / 256, blk, 0, stream>>>(uEmbd, iEmbd, Xf8);
    prep_weights<<<(2 * 80 * 64 + 255) / 256, blk, 0, stream>>>(w1, wi1, wtW, wtWi);

    // ---- CSR build ----
    hipMemsetAsync(deg, 0, 150000 * sizeof(int), stream);
    hipMemsetAsync(flag, 0, 150000 * sizeof(int), stream);
    hipMemsetAsync(selMap, 0xFF, 150000 * sizeof(int), stream);
    hist_kernel<<<(E + 255) / 256, blk, 0, stream>>>(rows, deg, E);
    int nScanBlocks = NSB;                              // 586
    scan_block<<<nScanBlocks, blk, 0, stream>>>(deg, ptr, bsum, N_NODES);
    scan_tops<<<1, dim3(1024), 0, stream>>>(bsum, nScanBlocks);
    scan_apply<<<nScanBlocks, blk, 0, stream>>>(ptr, bsum, pos, N_NODES);
    for (int s = 0; s < NSWEEP; s++) {
        scatter_sweep<<<(E + 255) / 256, blk, 0, stream>>>(
            rows, cols, vals, pos, ep, E, s * SWEEP_ROWS, (s + 1) * SWEEP_ROWS);
    }
    pad_ep<<<1, dim3(128), 0, stream>>>(ep);

    // ---- selMap + needed-row marking ----
    build_selmap<<<(2 * BATCH + 255) / 256, blk, 0, stream>>>(userIdx, itemIdx, selMap);
    mark_needed<<<(2 * BATCH + 3) / 4, blk, 0, stream>>>(
        userIdx, itemIdx, ptr, deg, ep, flag);

    // ---- degree bucket sorts (bin-major hist + flat parallel scan) ----
    int nHistBlocks = (NHIST + 255) / 256;              // 147
    deg_hist_blk<<<nScanBlocks, blk, 0, stream>>>(deg, nullptr, blockHistT, N_NODES);
    scan_block<<<nHistBlocks, blk, 0, stream>>>(blockHistT, scanT, bsum3, NHIST);
    scan_tops<<<1, dim3(1024), 0, stream>>>(bsum3, nHistBlocks);
    scan_apply_tot<<<nHistBlocks, blk, 0, stream>>>(scanT, bsum3, blockHistT, nullptr, NHIST);
    deg_scatter_blk<<<nScanBlocks, blk, 0, stream>>>(deg, nullptr, scanT, sortedAll, N_NODES);
    deg_hist_blk<<<nScanBlocks, blk, 0, stream>>>(deg, flag, blockHistT, N_NODES);
    scan_block<<<nHistBlocks, blk, 0, stream>>>(blockHistT, scanT, bsum3, NHIST);
    scan_tops<<<1, dim3(1024), 0, stream>>>(bsum3, nHistBlocks);
    scan_apply_tot<<<nHistBlocks, blk, 0, stream>>>(scanT, bsum3, blockHistT, cnt3, NHIST);
    deg_scatter_blk<<<nScanBlocks, blk, 0, stream>>>(deg, flag, scanT, sorted3, N_NODES);

    int grpGrid8 = (N_NODES + 31) / 32;       // 32 rows per block (8-lane groups)
    int grpGrid  = (N_NODES + 15) / 16;       // 16 rows per block (16-lane groups)
    int selGrid  = (2 * BATCH + 3) / 4;

    // ---- Layer 1 (F = 100) ----
    spmm_pass1<<<grpGrid8, blk, 0, stream>>>(
        sortedAll, ptr, deg, ep, Xf8, B1b, INTf8, N_NODES);
    spmm_pass2<<<grpGrid8, blk, 0, stream>>>(
        sortedAll, ptr, deg, ep, INTf8, B2b, N_NODES);
    {
        int grid = (N_NODES + 63) / 64;
        gemm1_mfma<<<grid, blk, 0, stream>>>(
            B1b, Xb64, B2b, wtW, wtWi, b1, bi1, selMap,
            (ushort_t*)F1b, F1sel, N_NODES);
    }

    // ---- Layer 2 (F = 80) ----
    spmm_pass3<<<grpGrid, blk, 0, stream>>>(
        sorted3, cnt3, ptr, deg, ep, F1b, selMap, Lxb, Lxsel);
    spmm_pass4<<<selGrid, blk, 0, stream>>>(
        ptr, deg, ep, Lxb, F1b, userIdx, itemIdx, B2c);
    {
        int grid = (2 * BATCH + 127) / 128;
        gemm_fused2_sel<<<grid, blk, 0, stream>>>(
            Lxsel, F1sel, selMap, B2c, w2, b2, wi2, bi2, userIdx, itemIdx, F2c);
    }

    // ---- Gather + MLP ----
    gather_embd<<<BATCH, dim3(128), 0, stream>>>(
        userIdx, itemIdx, uEmbd, iEmbd, F1sel, selMap, F2c, EMB);
    {
        constexpr int TPR = 8;
        int grid = (BATCH + (256 / TPR) - 1) / (256 / TPR);
        mlp_gemm<460, 64, TPR, true><<<grid, blk, 0, stream>>>(
            EMB, t1w, t1b, H1, BATCH);
    }
    {
        constexpr int TPR = 4;
        int grid = (BATCH + (256 / TPR) - 1) / (256 / TPR);
        mlp_gemm<64, 32, TPR, false><<<grid, blk, 0, stream>>>(
            H1, t2w, t2b, H2, BATCH);
    }
    {
        constexpr int TPR = 1;
        int grid = (BATCH + 255) / 256;
        mlp_gemm<32, 1, TPR, false><<<grid, blk, 0, stream>>>(
            H2, t3w, t3b, (float*)d_out, BATCH);
    }
}